// Round 2
// baseline (376.243 us; speedup 1.0000x reference)
//
#include <hip/hip_runtime.h>

// Binarize: x[2048,32768] f32, 3 thresholds -> packed bits (big-endian per byte)
// emitted as int32 values 0..255 (harness reads integer outputs as int32),
// shape [2048, 3, 4096].
// Memory-bound: 268 MB read + 101 MB write => ~59 us floor at 6.3 TB/s.

constexpr int B_ROWS = 2048;
constexpr int N_COLS = 32768;
constexpr int NB = N_COLS / 8;   // 4096 packed bytes per row per depth
constexpr int D = 3;

__global__ __launch_bounds__(256) void Binarize_52913997086767_kernel(
    const float* __restrict__ x,
    const float* __restrict__ ths,
    int* __restrict__ out)
{
    unsigned idx = blockIdx.x * 256u + threadIdx.x;   // 0 .. B_ROWS*NB-1
    unsigned row  = idx >> 12;                        // / 4096
    unsigned byte = idx & 4095u;                      // % 4096

    const float4* xp = reinterpret_cast<const float4*>(
        x + ((size_t)row << 15) + ((size_t)byte << 3));
    float4 v0 = xp[0];
    float4 v1 = xp[1];

    float t0 = ths[0];
    float t1 = ths[1];
    float t2 = ths[2];

    float vals[8] = {v0.x, v0.y, v0.z, v0.w, v1.x, v1.y, v1.z, v1.w};

    unsigned p0 = 0, p1 = 0, p2 = 0;
#pragma unroll
    for (int j = 0; j < 8; ++j) {
        // big-endian: element j gets weight 1<<(7-j) -> shift-left accumulate
        p0 = (p0 << 1) | (vals[j] > t0 ? 1u : 0u);
        p1 = (p1 << 1) | (vals[j] > t1 ? 1u : 0u);
        p2 = (p2 << 1) | (vals[j] > t2 ? 1u : 0u);
    }

    int* o = out + (size_t)row * (D * NB) + byte;
    o[0]      = (int)p0;
    o[NB]     = (int)p1;
    o[2 * NB] = (int)p2;
}

extern "C" void kernel_launch(void* const* d_in, const int* in_sizes, int n_in,
                              void* d_out, int out_size, void* d_ws, size_t ws_size,
                              hipStream_t stream) {
    const float* x   = (const float*)d_in[0];
    const float* ths = (const float*)d_in[1];
    int* out = (int*)d_out;

    const int total_threads = B_ROWS * NB;            // 8,388,608
    dim3 grid(total_threads / 256);                   // 32768 blocks
    dim3 block(256);
    Binarize_52913997086767_kernel<<<grid, block, 0, stream>>>(x, ths, out);
}